// Round 3
// baseline (1588.209 us; speedup 1.0000x reference)
//
#include <hip/hip_runtime.h>
#include <hip/hip_bf16.h>

typedef __attribute__((ext_vector_type(8))) short bf16x8;
typedef __attribute__((ext_vector_type(4))) float f32x4;
typedef __attribute__((ext_vector_type(2))) float f32x2;
typedef __attribute__((ext_vector_type(4))) unsigned int u32x4;

__device__ inline unsigned short f2bf(float f) {
    __hip_bfloat16 h = __float2bfloat16(f);
    return *reinterpret_cast<unsigned short*>(&h);
}
__device__ inline unsigned int pack2bf(float lo, float hi) {
    return (unsigned int)f2bf(lo) | ((unsigned int)f2bf(hi) << 16);
}

// ---------------------------------------------------------------------------
// GEMM: C[M][BN] = A[M][Kact] (f32) * BT^T  where BT is [BN][Kpad] bf16.
// BM=128, BK=64, 512 threads = 8 waves (2x4), per-wave 64 x (BN/4) tile.
// XOR-swizzled LDS (16B chunk index ^ (row&7)) -> ~2-way-banked ds_read_b128.
// f32->bf16 conversion fused into the reg-staged LDS write (A read once).
// ---------------------------------------------------------------------------
template<int BN, int KTILES>
__global__ __launch_bounds__(512, 1)
void gemm_bf16(const float* __restrict__ A, int lda, int Kact, int M,
               const unsigned short* __restrict__ BT, float* __restrict__ C)
{
    constexpr int Kpad = KTILES * 64;
    constexpr int SPAN = BN / 4;      // per-wave N span
    constexpr int NREP = SPAN / 16;   // 16x16 frags along N per wave

    __shared__ unsigned short Alds[128 * 64];
    __shared__ unsigned short Blds[BN * 64];

    const int tid  = threadIdx.x;
    const int lane = tid & 63;
    const int wid  = tid >> 6;
    const int wr   = wid >> 2;        // 0..1
    const int wc   = wid & 3;         // 0..3
    const int brow = blockIdx.x * 128;

    // --- A staging coords: thread t stages row (t>>2), k-quarter (t&3)*16 ---
    const int ar = tid >> 2;
    const int aq = tid & 3;
    int arow = brow + ar; if (arow >= M) arow = M - 1;
    const float* aptr = A + (size_t)arow * lda + aq * 16;
    const int aoff0 = ar * 64 + (((aq * 2    ) ^ (ar & 7)) << 3);
    const int aoff1 = ar * 64 + (((aq * 2 + 1) ^ (ar & 7)) << 3);

    // --- B staging coords: thread t (< BN*2) stages col (t>>1), half (t&1)*32 ---
    const int bcol  = tid >> 1;
    const int bhalf = tid & 1;
    const unsigned short* bptr = BT + (size_t)(bcol < BN ? bcol : 0) * Kpad + bhalf * 32;
    int boff[4];
    #pragma unroll
    for (int i = 0; i < 4; ++i)
        boff[i] = bcol * 64 + (((bhalf * 4 + i) ^ (bcol & 7)) << 3);

    // --- fragment read bases ---
    int arow_f[4];
    #pragma unroll
    for (int m = 0; m < 4; ++m)
        arow_f[m] = (wr * 64 + m * 16 + (lane & 15)) * 64;
    int bcol_f[NREP];
    #pragma unroll
    for (int n = 0; n < NREP; ++n)
        bcol_f[n] = (wc * SPAN + n * 16 + (lane & 15)) * 64;
    const int lsw    = lane & 7;    // == row&7 and col&7 for all frag rows/cols
    const int lchunk = lane >> 4;

    f32x4 acc[4][NREP];
    #pragma unroll
    for (int m = 0; m < 4; ++m)
        #pragma unroll
        for (int n = 0; n < NREP; ++n)
            acc[m][n] = (f32x4)(0.f);

    float areg[16];
    u32x4 breg[4];

    auto LOAD = [&](int t) {
        const int k0 = t * 64;
        if (k0 + 64 <= Kact) {
            #pragma unroll
            for (int i = 0; i < 4; ++i) {
                f32x4 v = *reinterpret_cast<const f32x4*>(aptr + k0 + i * 4);
                areg[i * 4 + 0] = v[0]; areg[i * 4 + 1] = v[1];
                areg[i * 4 + 2] = v[2]; areg[i * 4 + 3] = v[3];
            }
        } else {
            #pragma unroll
            for (int j = 0; j < 16; ++j) {
                int k = k0 + aq * 16 + j;
                areg[j] = (k < Kact) ? aptr[k0 + j] : 0.f;
            }
        }
        if (tid < BN * 2) {
            #pragma unroll
            for (int i = 0; i < 4; ++i)
                breg[i] = *reinterpret_cast<const u32x4*>(bptr + k0 + i * 8);
        }
    };

    auto WRITE = [&]() {
        u32x4 w0, w1;
        w0[0] = pack2bf(areg[0],  areg[1]);  w0[1] = pack2bf(areg[2],  areg[3]);
        w0[2] = pack2bf(areg[4],  areg[5]);  w0[3] = pack2bf(areg[6],  areg[7]);
        w1[0] = pack2bf(areg[8],  areg[9]);  w1[1] = pack2bf(areg[10], areg[11]);
        w1[2] = pack2bf(areg[12], areg[13]); w1[3] = pack2bf(areg[14], areg[15]);
        *reinterpret_cast<u32x4*>(&Alds[aoff0]) = w0;
        *reinterpret_cast<u32x4*>(&Alds[aoff1]) = w1;
        if (tid < BN * 2) {
            #pragma unroll
            for (int i = 0; i < 4; ++i)
                *reinterpret_cast<u32x4*>(&Blds[boff[i]]) = breg[i];
        }
    };

    auto COMPUTE = [&]() {
        #pragma unroll
        for (int h = 0; h < 2; ++h) {
            const int csw = (((h * 4 + lchunk) ^ lsw) << 3);
            bf16x8 af[4], bfv[NREP];
            #pragma unroll
            for (int m = 0; m < 4; ++m)
                af[m] = *reinterpret_cast<const bf16x8*>(&Alds[arow_f[m] + csw]);
            #pragma unroll
            for (int n = 0; n < NREP; ++n)
                bfv[n] = *reinterpret_cast<const bf16x8*>(&Blds[bcol_f[n] + csw]);
            #pragma unroll
            for (int m = 0; m < 4; ++m)
                #pragma unroll
                for (int n = 0; n < NREP; ++n)
                    acc[m][n] = __builtin_amdgcn_mfma_f32_16x16x32_bf16(
                        af[m], bfv[n], acc[m][n], 0, 0, 0);
        }
    };

    LOAD(0);
    for (int t = 0; t < KTILES; ++t) {
        WRITE();
        __syncthreads();
        if (t + 1 < KTILES) LOAD(t + 1);
        COMPUTE();
        __syncthreads();
    }

    // epilogue: C/D layout col=lane&15, row=(lane>>4)*4+j  [m89]
    #pragma unroll
    for (int m = 0; m < 4; ++m) {
        const int r0 = brow + wr * 64 + m * 16 + ((lane >> 4) << 2);
        #pragma unroll
        for (int n = 0; n < NREP; ++n) {
            const int gcol = wc * SPAN + n * 16 + (lane & 15);
            #pragma unroll
            for (int j = 0; j < 4; ++j) {
                const int gr = r0 + j;
                if (gr < M) C[(size_t)gr * BN + gcol] = acc[m][n][j];
            }
        }
    }
}

// ---------------------------------------------------------------------------
// CSR gather SpMM: out[i,:] = sum_e nrm[e]*H[col[e],:] + dis[i]^2*H[i,:] + b
// one wave per dst row, lanes across features; vectorized per-lane loads,
// 2-edge manual unroll so two gathers are in flight.
// ---------------------------------------------------------------------------
template<int F, bool RELU>
__global__ __launch_bounds__(256)
void spmm(const float* __restrict__ H, const int* __restrict__ rowptr,
          const int* __restrict__ colv, const float* __restrict__ nrm,
          const float* __restrict__ dis, const float* __restrict__ bias,
          float* __restrict__ out, int n)
{
    constexpr int VPL = F / 64;
    const int lane = threadIdx.x & 63;
    const int row = blockIdx.x * 4 + (threadIdx.x >> 6);
    if (row >= n) return;
    const int base = lane * VPL;

    float acc[VPL];
    #pragma unroll
    for (int j = 0; j < VPL; ++j) acc[j] = 0.f;

    auto GATHER = [&](int s, float w) {
        const float* hp = H + (size_t)s * F + base;
        if constexpr (VPL == 4) {
            f32x4 v = *reinterpret_cast<const f32x4*>(hp);
            acc[0] = fmaf(w, v[0], acc[0]); acc[1] = fmaf(w, v[1], acc[1]);
            acc[2] = fmaf(w, v[2], acc[2]); acc[3] = fmaf(w, v[3], acc[3]);
        } else if constexpr (VPL == 2) {
            f32x2 v = *reinterpret_cast<const f32x2*>(hp);
            acc[0] = fmaf(w, v[0], acc[0]); acc[1] = fmaf(w, v[1], acc[1]);
        } else {
            acc[0] = fmaf(w, hp[0], acc[0]);
        }
    };

    const int beg = rowptr[row], end = rowptr[row + 1];
    int e = beg;
    for (; e + 2 <= end; e += 2) {
        const int s0 = colv[e],     s1 = colv[e + 1];
        const float w0 = nrm[e],    w1 = nrm[e + 1];
        GATHER(s0, w0);
        GATHER(s1, w1);
    }
    if (e < end) GATHER(colv[e], nrm[e]);

    const float ds = dis[row];
    const float sw = ds * ds;
    const float* hp = H + (size_t)row * F + base;
    #pragma unroll
    for (int j = 0; j < VPL; ++j) {
        float v = acc[j] + sw * hp[j] + bias[base + j];
        if (RELU) v = fmaxf(v, 0.f);
        out[(size_t)row * F + base + j] = v;
    }
}

// ---------------------------------------------------------------------------
// preprocessing kernels  (edge_index arrives as int32 per harness contract)
// ---------------------------------------------------------------------------
__global__ void k_deg(const int* __restrict__ dst, int E, int* __restrict__ deg) {
    int i = blockIdx.x * 256 + threadIdx.x;
    if (i < E) atomicAdd(&deg[dst[i]], 1);
}

__global__ void k_dis(const int* __restrict__ deg, float* __restrict__ dis, int n) {
    int i = blockIdx.x * 256 + threadIdx.x;
    if (i < n) dis[i] = rsqrtf((float)deg[i] + 1.0f);
}

__global__ __launch_bounds__(1024)
void k_scan(const int* __restrict__ cnt, int n, int* __restrict__ rowptr, int* __restrict__ wptr) {
    __shared__ int sums[1024];
    const int tid = threadIdx.x;
    const int per = (n + 1023) / 1024;
    const int start = tid * per;
    const int lim = (start + per < n) ? (start + per) : n;
    int s = 0;
    for (int i = start; i < lim; ++i) s += cnt[i];
    sums[tid] = s;
    __syncthreads();
    for (int off = 1; off < 1024; off <<= 1) {
        int v = (tid >= off) ? sums[tid - off] : 0;
        __syncthreads();
        sums[tid] += v;
        __syncthreads();
    }
    int run = (tid > 0) ? sums[tid - 1] : 0;
    for (int i = start; i < lim; ++i) {
        rowptr[i] = run; wptr[i] = run; run += cnt[i];
    }
    if (tid == 0) rowptr[n] = sums[1023];
}

__global__ void k_scatter(const int* __restrict__ src, const int* __restrict__ dst,
                          int E, int* __restrict__ wptr, const float* __restrict__ dis,
                          int* __restrict__ colv, float* __restrict__ nrm) {
    int i = blockIdx.x * 256 + threadIdx.x;
    if (i < E) {
        const int s = src[i];
        const int d = dst[i];
        const int pos = atomicAdd(&wptr[d], 1);
        colv[pos] = s;
        nrm[pos] = dis[s] * dis[d];
    }
}

__global__ void k_transw(const float* __restrict__ W, int K, int Nn, int Kpad,
                         unsigned short* __restrict__ WT) {
    int idx = blockIdx.x * 256 + threadIdx.x;
    if (idx >= Nn * Kpad) return;
    const int nn = idx / Kpad;
    const int k = idx - nn * Kpad;
    const float v = (k < K) ? W[(size_t)k * Nn + nn] : 0.f;
    WT[idx] = f2bf(v);
}

__global__ __launch_bounds__(256)
void k_logit(const float* __restrict__ x3, const float* __restrict__ Wl,
             const float* __restrict__ bl, float* __restrict__ out, int n) {
    const int lane = threadIdx.x & 63;
    const int row = blockIdx.x * 4 + (threadIdx.x >> 6);
    if (row >= n) return;
    float v = x3[(size_t)row * 64 + lane] * Wl[lane];
    #pragma unroll
    for (int off = 32; off > 0; off >>= 1) v += __shfl_down(v, off);
    if (lane == 0) out[row] = 1.f / (1.f + expf(-(v + bl[0])));
}

// ---------------------------------------------------------------------------
extern "C" void kernel_launch(void* const* d_in, const int* in_sizes, int n_in,
                              void* d_out, int out_size, void* d_ws, size_t ws_size,
                              hipStream_t stream)
{
    const float* x   = (const float*)d_in[0];
    const int*   ei  = (const int*)d_in[1];     // int32 per harness contract
    const float* W1  = (const float*)d_in[2];
    const float* b1  = (const float*)d_in[3];
    const float* W2  = (const float*)d_in[4];
    const float* b2  = (const float*)d_in[5];
    const float* W3  = (const float*)d_in[6];
    const float* b3  = (const float*)d_in[7];
    const float* Wl  = (const float*)d_in[8];
    const float* bl  = (const float*)d_in[9];

    const int K1 = 3000;
    const int n = in_sizes[0] / K1;
    const int E = in_sizes[1] / 2;
    const int* esrc = ei;
    const int* edst = ei + E;

    char* ws = (char*)d_ws;
    size_t off = 0;
    auto alloc = [&](size_t bytes) -> char* {
        char* p = ws + off;
        off += (bytes + 255) & ~(size_t)255;
        return p;
    };
    int*   deg    = (int*)alloc((size_t)n * 4);
    float* dis    = (float*)alloc((size_t)n * 4);
    int*   rowptr = (int*)alloc((size_t)(n + 1) * 4);
    int*   wptr   = (int*)alloc((size_t)n * 4);
    int*   colv   = (int*)alloc((size_t)E * 4);
    float* nrm    = (float*)alloc((size_t)E * 4);
    unsigned short* w1t = (unsigned short*)alloc((size_t)256 * 3008 * 2);
    unsigned short* w2t = (unsigned short*)alloc((size_t)128 * 256 * 2);
    unsigned short* w3t = (unsigned short*)alloc((size_t)64 * 128 * 2);
    // lifetime-aliased activation buffers:
    //   bufA hosts h1 (gemm1 out), then h2 (gemm2 out), then h3 (gemm3 out)
    //   bufB hosts a1 (spmm1 out), then a2 (spmm2 out)
    char* bufA = alloc((size_t)n * 256 * 4);
    char* bufB = alloc((size_t)n * 256 * 4);
    float* h1 = (float*)bufA;
    float* a1 = (float*)bufB;
    float* h2 = (float*)bufA;
    float* a2 = (float*)bufB;
    float* h3 = (float*)bufA;

    float* outp = (float*)d_out;   // [n] sigmoid output
    float* x3   = outp + n;        // [n][64]

    hipMemsetAsync(deg, 0, (size_t)n * 4, stream);

    k_deg<<<(E + 255) / 256, 256, 0, stream>>>(edst, E, deg);
    k_dis<<<(n + 255) / 256, 256, 0, stream>>>(deg, dis, n);
    k_scan<<<1, 1024, 0, stream>>>(deg, n, rowptr, wptr);
    k_scatter<<<(E + 255) / 256, 256, 0, stream>>>(esrc, edst, E, wptr, dis, colv, nrm);

    k_transw<<<(256 * 3008 + 255) / 256, 256, 0, stream>>>(W1, K1, 256, 3008, w1t);
    k_transw<<<(128 * 256 + 255) / 256, 256, 0, stream>>>(W2, 256, 128, 256, w2t);
    k_transw<<<(64 * 128 + 255) / 256, 256, 0, stream>>>(W3, 128, 64, 128, w3t);

    const int mblocks = (n + 127) / 128;
    gemm_bf16<256, 47><<<mblocks, 512, 0, stream>>>(x,  K1,  K1,  n, w1t, h1);
    spmm<256, true ><<<(n + 3) / 4, 256, 0, stream>>>(h1, rowptr, colv, nrm, dis, b1, a1, n);
    gemm_bf16<128, 4 ><<<mblocks, 512, 0, stream>>>(a1, 256, 256, n, w2t, h2);
    spmm<128, false><<<(n + 3) / 4, 256, 0, stream>>>(h2, rowptr, colv, nrm, dis, b2, a2, n);
    gemm_bf16<64,  2 ><<<mblocks, 512, 0, stream>>>(a2, 128, 128, n, w3t, h3);
    spmm<64,  false><<<(n + 3) / 4, 256, 0, stream>>>(h3, rowptr, colv, nrm, dis, b3, x3, n);
    k_logit<<<(n + 3) / 4, 256, 0, stream>>>(x3, Wl, bl, outp, n);
}